// Round 14
// baseline (212.988 us; speedup 1.0000x reference)
//
#include <hip/hip_runtime.h>

#define B_ 2
#define T_ 2048
#define D_ 2048
#define H_ 16
#define KV_ 4
#define HD_ 128
#define M_ (B_*T_)   // 4096

typedef __attribute__((ext_vector_type(8))) short s8v;
typedef __attribute__((ext_vector_type(4))) float f4v;
typedef __attribute__((ext_vector_type(16))) float f16v;
typedef __attribute__((ext_vector_type(8))) __bf16 b8v;
typedef __attribute__((ext_vector_type(4))) unsigned u4v;

__device__ __forceinline__ short f2bs(float f) {
  unsigned u = __builtin_bit_cast(unsigned, f);
  u += 0x7fffu + ((u >> 16) & 1u);
  return (short)(u >> 16);
}
__device__ __forceinline__ float bs2f(short s) {
  unsigned u = ((unsigned)(unsigned short)s) << 16;
  return __builtin_bit_cast(float, u);
}
// swap hi-half of x with lo-half of y (distinct values only!)
__device__ __forceinline__ void plswap2(unsigned &x, unsigned &y) {
  asm volatile("v_permlane32_swap_b32 %0, %1" : "+v"(x), "+v"(y));
}
__device__ __forceinline__ unsigned cvtpk(float lo, float hi) {
  unsigned r;
  asm("v_cvt_pk_bf16_f32 %0, %1, %2" : "=v"(r) : "v"(lo), "v"(hi));
  return r;
}

// ---------------- merged prep: weight tcast + hs cast + pad-mask precompute ----------------
__global__ void prep_kernel(const float* __restrict__ hs,
                            const float* __restrict__ Wq, const float* __restrict__ Wk,
                            const float* __restrict__ Wv, const float* __restrict__ Wo,
                            short* __restrict__ hsb,
                            short* __restrict__ WT, short* __restrict__ WoT,
                            const int* __restrict__ ids,
                            unsigned long long* __restrict__ pmA) {
  int bid = blockIdx.x;
  const int tid = threadIdx.y * 32 + threadIdx.x;
  if (bid >= 10240) {
    const int i = (bid - 10240) * 256 + tid;
    float4 v = reinterpret_cast<const float4*>(hs)[i];
    short4 o;
    o.x = f2bs(v.x); o.y = f2bs(v.y); o.z = f2bs(v.z); o.w = f2bs(v.w);
    reinterpret_cast<short4*>(hsb)[i] = o;
    return;
  }
  if (bid == 0 && tid < 64) {
    // pad mask for (batch bb, kv-tile tt): bit k = (ids[bb*T + tt*64 + k] != 0)
    const int bb = tid >> 5, tt = tid & 31;
    const int* p = ids + bb*T_ + tt*64;
    unsigned long long m = 0;
    for (int k = 0; k < 64; ++k) m |= (unsigned long long)(p[k] != 0) << k;
    pmA[tid] = m;
  }
  __shared__ float t[32][33];
  const float* W; short* dst; int N, rowoff;
  if (bid < 4096)      { W = Wq; dst = WT;  N = 2048; rowoff = 0;    }
  else if (bid < 5120) { W = Wk; dst = WT;  N = 512;  rowoff = 2048; bid -= 4096; }
  else if (bid < 6144) { W = Wv; dst = WT;  N = 512;  rowoff = 2560; bid -= 5120; }
  else                 { W = Wo; dst = WoT; N = 2048; rowoff = 0;    bid -= 6144; }
  const int nbl = N >> 5;
  const int nb = (bid % nbl) * 32, kb = (bid / nbl) * 32;
  const int tx = threadIdx.x, ty = threadIdx.y;
#pragma unroll
  for (int j = 0; j < 4; ++j)
    t[ty + j*8][tx] = W[(size_t)(kb + ty + j*8) * N + nb + tx];
  __syncthreads();
#pragma unroll
  for (int j = 0; j < 4; ++j)
    dst[(size_t)(rowoff + nb + ty + j*8) * 2048 + kb + tx] = f2bs(t[tx][ty + j*8]);
}

// ---------------- GEMM (R13 structure, unchanged): 3-ring, counted vmcnt, swizzled ----------------
template<int MODE>
__global__ __launch_bounds__(256) void gemm_bt_kernel(const short* __restrict__ A,
                                                      const short* __restrict__ BT,
                                                      void* __restrict__ Cv,
                                                      short* __restrict__ Kv,
                                                      short* __restrict__ Vt,
                                                      int M, int N, int K) {
  __shared__ alignas(16) short As[3][128*32];
  __shared__ alignas(16) short Bs[3][128*32];
  const int tid  = threadIdx.x;
  const int wave = tid >> 6;
  const int lane = tid & 63;
  const int lr = lane & 15;
  const int lk = (((lane >> 4) ^ ((lr >> 1) & 3)) * 8);   // swizzled chunk offset
  const int m0 = blockIdx.y * 128;
  const int n0 = blockIdx.x * 128;
  const int wr = (wave >> 1) * 64;
  const int wc = (wave & 1) * 64;

  const int srow = tid >> 2;
  const int skc  = (tid & 3) ^ ((srow >> 1) & 3);         // pre-swizzled source chunk
  const short* gaBase  = A  + (size_t)(m0 + srow) * K + skc*8;
  const short* gbBase  = BT + (size_t)(n0 + srow) * K + skc*8;
  const short* gaBase2 = A  + (size_t)(m0 + 64 + srow) * K + skc*8;
  const short* gbBase2 = BT + (size_t)(n0 + 64 + srow) * K + skc*8;
  const int ldsOff  = (wave*64) * 8;
  const int ldsOff2 = (256 + wave*64) * 8;

  f4v acc[4][4];
#pragma unroll
  for (int m = 0; m < 4; ++m)
#pragma unroll
    for (int n = 0; n < 4; ++n) acc[m][n] = (f4v)0.0f;

  auto STAGE = [&](int tile, int slot) {
    const int kn = tile * 32;
    short* a1 = &As[slot][0];
    short* b1 = &Bs[slot][0];
    __builtin_amdgcn_global_load_lds((const __attribute__((address_space(1))) void*)(gaBase + kn),
        (__attribute__((address_space(3))) void*)(a1 + ldsOff), 16, 0, 0);
    __builtin_amdgcn_global_load_lds((const __attribute__((address_space(1))) void*)(gbBase + kn),
        (__attribute__((address_space(3))) void*)(b1 + ldsOff), 16, 0, 0);
    __builtin_amdgcn_global_load_lds((const __attribute__((address_space(1))) void*)(gaBase2 + kn),
        (__attribute__((address_space(3))) void*)(a1 + ldsOff2), 16, 0, 0);
    __builtin_amdgcn_global_load_lds((const __attribute__((address_space(1))) void*)(gbBase2 + kn),
        (__attribute__((address_space(3))) void*)(b1 + ldsOff2), 16, 0, 0);
  };

  const int NT = K >> 5;
  STAGE(0, 0);
  STAGE(1, 1);
  asm volatile("s_waitcnt vmcnt(4)" ::: "memory");
  __builtin_amdgcn_s_barrier();
  __builtin_amdgcn_sched_barrier(0);

  for (int t = 0; t < NT; ++t) {
    if (t + 2 < NT) STAGE(t + 2, (t + 2) % 3);
    const short* Ac = &As[t % 3][0];
    const short* Bc = &Bs[t % 3][0];
    s8v af[4], bfv[4];
#pragma unroll
    for (int m = 0; m < 4; ++m)
      af[m] = *reinterpret_cast<const s8v*>(Ac + (wr + m*16 + lr)*32 + lk);
#pragma unroll
    for (int n = 0; n < 4; ++n)
      bfv[n] = *reinterpret_cast<const s8v*>(Bc + (wc + n*16 + lr)*32 + lk);
#pragma unroll
    for (int m = 0; m < 4; ++m)
#pragma unroll
      for (int n = 0; n < 4; ++n)
        acc[m][n] = __builtin_amdgcn_mfma_f32_16x16x32_bf16(
            __builtin_bit_cast(b8v, af[m]), __builtin_bit_cast(b8v, bfv[n]),
            acc[m][n], 0, 0, 0);
    if (t + 1 < NT) {
      if (t < NT - 2) { asm volatile("s_waitcnt vmcnt(4)" ::: "memory"); }
      else            { asm volatile("s_waitcnt vmcnt(0)" ::: "memory"); }
      __builtin_amdgcn_s_barrier();
      __builtin_amdgcn_sched_barrier(0);
    }
  }

  if (MODE == 3 && n0 >= 2560) {
#pragma unroll
    for (int m = 0; m < 4; ++m) {
#pragma unroll
      for (int n = 0; n < 4; ++n) {
        const int col = n0 + wc + n*16 + lr - 2560;
        const int row = m0 + wr + m*16 + (lane >> 4)*4;
        short4 o;
        o.x = f2bs(acc[m][n][0]); o.y = f2bs(acc[m][n][1]);
        o.z = f2bs(acc[m][n][2]); o.w = f2bs(acc[m][n][3]);
        *reinterpret_cast<short4*>(Vt + (size_t)col * M + row) = o;
      }
    }
  } else {
#pragma unroll
    for (int m = 0; m < 4; ++m) {
#pragma unroll
      for (int n = 0; n < 4; ++n) {
#pragma unroll
        for (int i = 0; i < 4; ++i) {
          const int row = m0 + wr + m*16 + (lane >> 4)*4 + i;
          const int col = n0 + wc + n*16 + lr;
          if (MODE == 1)
            reinterpret_cast<float*>(Cv)[(size_t)row * N + col] = acc[m][n][i];
          else if (col < 2048)
            reinterpret_cast<short*>(Cv)[(size_t)row * 2048 + col] = f2bs(acc[m][n][i]);
          else
            Kv[(size_t)row * 512 + (col - 2048)] = f2bs(acc[m][n][i]);
        }
      }
    }
  }
}

// ---------------- flash attention: kv-split + prefetched pad masks + 4-chain QK ----------------
__device__ __forceinline__ void stage_tile(short* KsBuf, short* VtBuf,
                                           const short* __restrict__ Kb,
                                           const short* __restrict__ Vtg,
                                           int bT, int kv0, int kvh,
                                           int tid, int wave) {
#pragma unroll
  for (int j = 0; j < 4; ++j) {
    const int f = j*256 + tid;
    const int row = f >> 4, cd = f & 15, cs = cd ^ (row & 7);
    const short* g = Kb + (size_t)(bT + kv0 + row)*512 + kvh*HD_ + cs*8;
    short* l = KsBuf + (j*256 + wave*64) * 8;
    __builtin_amdgcn_global_load_lds((const __attribute__((address_space(1))) void*)g,
                                     (__attribute__((address_space(3))) void*)l, 16, 0, 0);
  }
#pragma unroll
  for (int j = 0; j < 4; ++j) {
    const int f = j*256 + tid;
    const int d = f >> 3, cd = f & 7, cs = cd ^ (d & 7);
    const short* g = Vtg + (size_t)(kvh*HD_ + d)*M_ + bT + kv0 + cs*8;
    short* l = VtBuf + (j*256 + wave*64) * 8;
    __builtin_amdgcn_global_load_lds((const __attribute__((address_space(1))) void*)g,
                                     (__attribute__((address_space(3))) void*)l, 16, 0, 0);
  }
}

#define PHALF 33792   // 32768 O + 512 m + 512 l
#define PGI   67584   // 2 halves

__global__ __launch_bounds__(256, 2) void attn_kernel(const short* __restrict__ Q,
                                                      const short* __restrict__ Kb,
                                                      const short* __restrict__ Vtg,
                                                      const unsigned long long* __restrict__ pmA,
                                                      short* __restrict__ AO,
                                                      char* __restrict__ pbuf) {
  __shared__ alignas(16) short Ks[2][64*128];
  __shared__ alignas(16) short Vt[2][128*64];

  // ---- decode bid -> (p, bh, split, half), longest-serial-first order ----
  const int bid = blockIdx.x;
  int p, bh, split = 0, half = 0, r;
  if      (bid <  32) { p = 10; bh = bid;       }
  else if (bid <  64) { p = 9;  bh = bid - 32;  }
  else if (bid <  96) { p = 8;  bh = bid - 64;  }
  else if (bid < 160) { p = 15; r = bid - 96;  bh = r >> 1; half = r & 1; split = 1; }
  else if (bid < 192) { p = 7;  bh = bid - 160; }
  else if (bid < 256) { p = 14; r = bid - 192; bh = r >> 1; half = r & 1; split = 1; }
  else if (bid < 320) { p = 13; r = bid - 256; bh = r >> 1; half = r & 1; split = 1; }
  else if (bid < 352) { p = 6;  bh = bid - 320; }
  else if (bid < 416) { p = 12; r = bid - 352; bh = r >> 1; half = r & 1; split = 1; }
  else if (bid < 448) { p = 5;  bh = bid - 416; }
  else if (bid < 512) { p = 11; r = bid - 448; bh = r >> 1; half = r & 1; split = 1; }
  else if (bid < 544) { p = 4;  bh = bid - 512; }
  else if (bid < 576) { p = 3;  bh = bid - 544; }
  else if (bid < 608) { p = 2;  bh = bid - 576; }
  else if (bid < 640) { p = 1;  bh = bid - 608; }
  else                { p = 0;  bh = bid - 640; }

  const int h   = bh & (H_-1);
  const int b   = bh >> 4;
  const int kvh = h & (KV_-1);
  const int nt  = 2*(p+1);
  const int ht  = p + 1;
  const int t0  = (split && half) ? ht : 0;
  const int t1  = split ? (half ? nt : ht) : nt;

  const int tid = threadIdx.x;
  const int wq  = tid >> 6;
  const int lane = tid & 63;
  const int ql  = lane & 31;
  const int hi  = lane >> 5;
  const int bT  = b * T_;
  const int q0  = p * 128;
  const int qrow = q0 + wq*32 + ql;
  const int pmBase = b * 32;
  const float SC = 0.08838834764831845f * 1.4426950408889634f;

  s8v qf[8];
  const size_t qgbase = (size_t)(bT + qrow) * (H_*HD_) + h*HD_;
#pragma unroll
  for (int mm = 0; mm < 8; ++mm)
    qf[mm] = *reinterpret_cast<const s8v*>(Q + qgbase + mm*16 + hi*8);

  f16v oacc[4];
#pragma unroll
  for (int n = 0; n < 4; ++n) oacc[n] = (f16v)0.0f;
  float m_run = -1.0e30f, lsum = 0.0f;

  stage_tile(Ks[0], Vt[0], Kb, Vtg, bT, t0*64, kvh, tid, wq);
  unsigned long long pm_cur = pmA[pmBase + t0];   // hides under staging/Q-load
  int cur = 0;
  for (int t = t0; t < t1; ++t) {
    __syncthreads();
    if (t + 1 < t1)
      stage_tile(Ks[cur^1], Vt[cur^1], Kb, Vtg, bT, (t+1)*64, kvh, tid, wq);
    // prefetch next tile's pad mask — latency hides under this tile's compute
    const unsigned long long pm_next = (t + 1 < t1) ? pmA[pmBase + t + 1] : 0ull;
    const int kv0 = t * 64;
    const char* KsC = reinterpret_cast<const char*>(Ks[cur]);
    const char* VtC = reinterpret_cast<const char*>(Vt[cur]);

    // S^T = K Q^T : 4 independent MFMA chains (2 kb x 2 mm-halves) for ILP
    f16v s0a = (f16v)0.0f, s0b = (f16v)0.0f, s1a = (f16v)0.0f, s1b = (f16v)0.0f;
#pragma unroll
    for (int mm = 0; mm < 4; ++mm) {
      const int row0 = ql, row1 = 32 + ql;
      s8v kf0 = *reinterpret_cast<const s8v*>(KsC +
          ((row0*256 + mm*32 + hi*16) ^ ((row0 & 7) << 4)));
      s8v kf1 = *reinterpret_cast<const s8v*>(KsC +
          ((row1*256 + mm*32 + hi*16) ^ ((row1 & 7) << 4)));
      s0a = __builtin_amdgcn_mfma_f32_32x32x16_bf16(
          __builtin_bit_cast(b8v, kf0), __builtin_bit_cast(b8v, qf[mm]), s0a, 0, 0, 0);
      s1a = __builtin_amdgcn_mfma_f32_32x32x16_bf16(
          __builtin_bit_cast(b8v, kf1), __builtin_bit_cast(b8v, qf[mm]), s1a, 0, 0, 0);
    }
#pragma unroll
    for (int mm = 4; mm < 8; ++mm) {
      const int row0 = ql, row1 = 32 + ql;
      s8v kf0 = *reinterpret_cast<const s8v*>(KsC +
          ((row0*256 + mm*32 + hi*16) ^ ((row0 & 7) << 4)));
      s8v kf1 = *reinterpret_cast<const s8v*>(KsC +
          ((row1*256 + mm*32 + hi*16) ^ ((row1 & 7) << 4)));
      s0b = __builtin_amdgcn_mfma_f32_32x32x16_bf16(
          __builtin_bit_cast(b8v, kf0), __builtin_bit_cast(b8v, qf[mm]), s0b, 0, 0, 0);
      s1b = __builtin_amdgcn_mfma_f32_32x32x16_bf16(
          __builtin_bit_cast(b8v, kf1), __builtin_bit_cast(b8v, qf[mm]), s1b, 0, 0, 0);
    }
    f16v sacc[2];
    sacc[0] = s0a + s0b;
    sacc[1] = s1a + s1b;

    float tm[16];
#pragma unroll
    for (int rr = 0; rr < 16; ++rr) tm[rr] = fmaxf(sacc[0][rr], sacc[1][rr]);
#pragma unroll
    for (int rr = 0; rr < 8; ++rr) tm[rr] = fmaxf(tm[rr], tm[rr+8]);
#pragma unroll
    for (int rr = 0; rr < 4; ++rr) tm[rr] = fmaxf(tm[rr], tm[rr+4]);
    tm[0] = fmaxf(fmaxf(tm[0], tm[1]), fmaxf(tm[2], tm[3]));
    const float mx = fmaxf(tm[0], __shfl_xor(tm[0], 32));

    if (!__all(mx <= m_run + 20.0f)) {
      const float mn = fmaxf(m_run, mx);
      const float corr = exp2f((m_run - mn) * SC);
      lsum *= corr;
#pragma unroll
      for (int n = 0; n < 4; ++n)
#pragma unroll
        for (int rr = 0; rr < 16; ++rr) oacc[n][rr] *= corr;
      m_run = mn;
    }
    const float nm = -m_run * SC;
    const bool fast = (kv0 + 63 <= q0 + wq*32) && (pm_cur == ~0ull);

    float psum = 0.0f;
#pragma unroll
    for (int kb = 0; kb < 2; ++kb) {
      float pv[16];
#pragma unroll
      for (int rr = 0; rr < 16; ++rr)
        pv[rr] = exp2f(fmaf(sacc[kb][rr], SC, nm));
      if (!fast) {
        const int th = qrow - kv0 - kb*32 - 4*hi;
        const unsigned cw = (th >= 28) ? 0xffffffffu
                          : ((th < 0) ? 0u : ((2u << th) - 1u));
        const unsigned vm = cw & (unsigned)(pm_cur >> (kb*32 + 4*hi));
#pragma unroll
        for (int rr = 0; rr < 16; ++rr) {
          const int C = (rr & 3) + 8*(rr >> 2);
          pv[rr] = ((vm >> C) & 1u) ? pv[rr] : 0.0f;
        }
      }
      float ps[8];
#pragma unroll
      for (int rr = 0; rr < 8; ++rr) ps[rr] = pv[rr] + pv[rr+8];
#pragma unroll
      for (int rr = 0; rr < 4; ++rr) ps[rr] += ps[rr+4];
      psum += (ps[0] + ps[1]) + (ps[2] + ps[3]);

      unsigned pa = cvtpk(pv[0],  pv[1]),  pb = cvtpk(pv[2],  pv[3]);
      unsigned pc = cvtpk(pv[4],  pv[5]),  pd = cvtpk(pv[6],  pv[7]);
      unsigned pe = cvtpk(pv[8],  pv[9]),  pf_ = cvtpk(pv[10], pv[11]);
      unsigned pg = cvtpk(pv[12], pv[13]), ph = cvtpk(pv[14], pv[15]);
      plswap2(pa, pc);  plswap2(pb, pd);
      plswap2(pe, pg);  plswap2(pf_, ph);
      u4v pw0 = {pa, pb, pc, pd};
      u4v pw1 = {pe, pf_, pg, ph};

#pragma unroll
      for (int s = 0; s < 2; ++s) {
        const b8v pf = __builtin_bit_cast(b8v, s ? pw1 : pw0);
        const int ks = 2*kb + s;
#pragma unroll
        for (int n = 0; n < 4; ++n) {
          const int d = n*32 + ql;
          s8v vf = *reinterpret_cast<const s8v*>(VtC +
              ((d*128 + ks*32 + hi*16) ^ ((d & 7) << 4)));
          oacc[n] = __builtin_amdgcn_mfma_f32_32x32x16_bf16(
              __builtin_bit_cast(b8v, vf), pf, oacc[n], 0, 0, 0);
        }
      }
    }
    lsum += psum + __shfl_xor(psum, 32);
    pm_cur = pm_next;
    cur ^= 1;
  }

  if (!split) {
    const float inv = 1.0f / fmaxf(lsum, 1.0e-37f);
    const size_t obase = (size_t)(bT + qrow) * (H_*HD_) + h*HD_;
#pragma unroll
    for (int n = 0; n < 4; ++n) {
#pragma unroll
      for (int j = 0; j < 4; ++j) {
        short4 o;
        o.x = f2bs(oacc[n][4*j+0] * inv);
        o.y = f2bs(oacc[n][4*j+1] * inv);
        o.z = f2bs(oacc[n][4*j+2] * inv);
        o.w = f2bs(oacc[n][4*j+3] * inv);
        *reinterpret_cast<short4*>(AO + obase + n*32 + 8*j + 4*hi) = o;
      }
    }
  } else {
    char* pg = pbuf + (size_t)(bh*5 + (p - 11)) * PGI + half * PHALF;
    short* pO = (short*)pg;
    float* pM = (float*)(pg + 32768);
    float* pL = (float*)(pg + 33280);
    const int row = wq*32 + ql;
#pragma unroll
    for (int n = 0; n < 4; ++n) {
#pragma unroll
      for (int j = 0; j < 4; ++j) {
        short4 o;
        o.x = f2bs(oacc[n][4*j+0]);
        o.y = f2bs(oacc[n][4*j+1]);
        o.z = f2bs(oacc[n][4*j+2]);
        o.w = f2bs(oacc[n][4*j+3]);
        *reinterpret_cast<short4*>(pO + row*128 + n*32 + 8*j + 4*hi) = o;
      }
    }
    if (hi == 0) { pM[row] = m_run; pL[row] = lsum; }
  }
}

// ---------------- combine: merge the two kv-halves of each split q-tile ----------------
__global__ __launch_bounds__(256) void combine_kernel(const char* __restrict__ pbuf,
                                                      short* __restrict__ AO) {
  const int gi = blockIdx.x;                 // 0..159
  const int bh = gi / 5, pp = gi % 5, p = 11 + pp;
  const int h = bh & (H_-1), b = bh >> 4;
  const char* g0 = pbuf + (size_t)gi * PGI;
  const char* g1 = g0 + PHALF;
  const int t = threadIdx.x;
  const int row = t >> 1, dh = (t & 1) * 64;
  const float SC = 0.08838834764831845f * 1.4426950408889634f;

  const float m1 = ((const float*)(g0 + 32768))[row];
  const float l1 = ((const float*)(g0 + 33280))[row];
  const float m2 = ((const float*)(g1 + 32768))[row];
  const float l2 = ((const float*)(g1 + 33280))[row];
  const float m  = fmaxf(m1, m2);
  const float w1 = exp2f((m1 - m) * SC);
  const float w2 = exp2f((m2 - m) * SC);
  const float inv = 1.0f / fmaxf(w1*l1 + w2*l2, 1.0e-37f);

  const short* O1 = (const short*)g0 + row*128 + dh;
  const short* O2 = (const short*)g1 + row*128 + dh;
  short* dst = AO + (size_t)(b*T_ + p*128 + row) * (H_*HD_) + h*HD_ + dh;
#pragma unroll
  for (int c = 0; c < 8; ++c) {
    s8v a = *reinterpret_cast<const s8v*>(O1 + c*8);
    s8v v = *reinterpret_cast<const s8v*>(O2 + c*8);
    s8v o;
#pragma unroll
    for (int e = 0; e < 8; ++e)
      o[e] = f2bs((w1 * bs2f(a[e]) + w2 * bs2f(v[e])) * inv);
    *reinterpret_cast<s8v*>(dst + c*8) = o;
  }
}

// ---------------- launcher ----------------
extern "C" void kernel_launch(void* const* d_in, const int* in_sizes, int n_in,
                              void* d_out, int out_size, void* d_ws, size_t ws_size,
                              hipStream_t stream) {
  const float* hs = (const float*)d_in[0];
  const int*  ids = (const int*)d_in[1];
  const float* Wq = (const float*)d_in[2];
  const float* Wk = (const float*)d_in[3];
  const float* Wv = (const float*)d_in[4];
  const float* Wo = (const float*)d_in[5];
  char* ws = (char*)d_ws;

  short* hsb = (short*)(ws);                          // 16 MiB, reused as AO
  short* WT  = (short*)(ws + (16u << 20));            // 12 MiB, reused as pbuf after QKV
  short* WoT = (short*)(ws + (28u << 20));            // 8 MiB
  short* Qb  = (short*)(ws + (36u << 20));            // 16 MiB
  short* Kb  = (short*)(ws + (52u << 20));            // 4 MiB
  short* Vtg = (short*)(ws + (56u << 20));            // 4 MiB
  short* AO  = hsb;
  char*  pbuf = (char*)WT;                            // partials (WT dead post-QKV)
  float* out = (float*)d_out;
  // pad-mask scratch: first 512 B of d_out (written by prep, read by attn,
  // fully overwritten by the O-projection GEMM)
  unsigned long long* pmA = (unsigned long long*)d_out;

  prep_kernel<<<dim3(18432), dim3(32, 8), 0, stream>>>(hs, Wq, Wk, Wv, Wo, hsb, WT, WoT, ids, pmA);

  gemm_bt_kernel<3><<<dim3(3072/128, 4096/128), dim3(256), 0, stream>>>(
      hsb, WT, Qb, Kb, Vtg, 4096, 3072, 2048);

  attn_kernel<<<dim3(672), dim3(256), 0, stream>>>(Qb, Kb, Vtg, pmA, AO, pbuf);
  combine_kernel<<<dim3(160), dim3(256), 0, stream>>>(pbuf, AO);

  gemm_bt_kernel<1><<<dim3(2048/128, 4096/128), dim3(256), 0, stream>>>(
      AO, WoT, out, nullptr, nullptr, 4096, 2048, 2048);
}

// Round 15
// 197.352 us; speedup vs baseline: 1.0792x; 1.0792x over previous
//
#include <hip/hip_runtime.h>

#define B_ 2
#define T_ 2048
#define D_ 2048
#define H_ 16
#define KV_ 4
#define HD_ 128
#define M_ (B_*T_)   // 4096

typedef __attribute__((ext_vector_type(8))) short s8v;
typedef __attribute__((ext_vector_type(4))) float f4v;
typedef __attribute__((ext_vector_type(16))) float f16v;
typedef __attribute__((ext_vector_type(8))) __bf16 b8v;
typedef __attribute__((ext_vector_type(4))) unsigned u4v;

__device__ __forceinline__ short f2bs(float f) {
  unsigned u = __builtin_bit_cast(unsigned, f);
  u += 0x7fffu + ((u >> 16) & 1u);
  return (short)(u >> 16);
}
__device__ __forceinline__ float bs2f(short s) {
  unsigned u = ((unsigned)(unsigned short)s) << 16;
  return __builtin_bit_cast(float, u);
}
__device__ __forceinline__ void plswap2(unsigned &x, unsigned &y) {
  asm volatile("v_permlane32_swap_b32 %0, %1" : "+v"(x), "+v"(y));
}
__device__ __forceinline__ unsigned cvtpk(float lo, float hi) {
  unsigned r;
  asm("v_cvt_pk_bf16_f32 %0, %1, %2" : "=v"(r) : "v"(lo), "v"(hi));
  return r;
}

// ---------------- merged prep: weight tcast + hs cast + pad-mask precompute ----------------
__global__ void prep_kernel(const float* __restrict__ hs,
                            const float* __restrict__ Wq, const float* __restrict__ Wk,
                            const float* __restrict__ Wv, const float* __restrict__ Wo,
                            short* __restrict__ hsb,
                            short* __restrict__ WT, short* __restrict__ WoT,
                            const int* __restrict__ ids,
                            unsigned long long* __restrict__ pmA) {
  int bid = blockIdx.x;
  const int tid = threadIdx.y * 32 + threadIdx.x;
  if (bid >= 10240) {
    const int i = (bid - 10240) * 256 + tid;
    float4 v = reinterpret_cast<const float4*>(hs)[i];
    short4 o;
    o.x = f2bs(v.x); o.y = f2bs(v.y); o.z = f2bs(v.z); o.w = f2bs(v.w);
    reinterpret_cast<short4*>(hsb)[i] = o;
    return;
  }
  if (bid == 0 && tid < 64) {
    const int bb = tid >> 5, tt = tid & 31;
    const int* p = ids + bb*T_ + tt*64;
    unsigned long long m = 0;
    for (int k = 0; k < 64; ++k) m |= (unsigned long long)(p[k] != 0) << k;
    pmA[tid] = m;
  }
  __shared__ float t[32][33];
  const float* W; short* dst; int N, rowoff;
  if (bid < 4096)      { W = Wq; dst = WT;  N = 2048; rowoff = 0;    }
  else if (bid < 5120) { W = Wk; dst = WT;  N = 512;  rowoff = 2048; bid -= 4096; }
  else if (bid < 6144) { W = Wv; dst = WT;  N = 512;  rowoff = 2560; bid -= 5120; }
  else                 { W = Wo; dst = WoT; N = 2048; rowoff = 0;    bid -= 6144; }
  const int nbl = N >> 5;
  const int nb = (bid % nbl) * 32, kb = (bid / nbl) * 32;
  const int tx = threadIdx.x, ty = threadIdx.y;
#pragma unroll
  for (int j = 0; j < 4; ++j)
    t[ty + j*8][tx] = W[(size_t)(kb + ty + j*8) * N + nb + tx];
  __syncthreads();
#pragma unroll
  for (int j = 0; j < 4; ++j)
    dst[(size_t)(rowoff + nb + ty + j*8) * 2048 + kb + tx] = f2bs(t[tx][ty + j*8]);
}

// ---------------- GEMM: 256x256 tile, 8 waves, BK=64, deep pipeline ----------------
// Per K-tile: 4 quadrant phases (16 MFMA each, setprio-wrapped); panels of
// K-tile t+1 staged in phases 0-1 into the non-computed dbuf (slots free since
// the iter-start barrier); ONE vmcnt(0)+s_barrier+sched_barrier per K-tile,
// with staging loads 2-3 phases old at the drain. Chunk-XOR swizzle c^=(row&7)
// (source-pre-swizzled, linear gload_lds dest) -> fragment reads at the
// 8-lanes/quad structural minimum.
// MODE 1: f32 out. MODE 3: QKV split (Q | K | V^T).
template<int MODE>
__global__ __launch_bounds__(512, 2) void gemm_bt_kernel(const short* __restrict__ A,
                                                         const short* __restrict__ BT,
                                                         void* __restrict__ Cv,
                                                         short* __restrict__ Kv,
                                                         short* __restrict__ Vt,
                                                         int M, int N, int K) {
  __shared__ alignas(16) short LDS[2*32768];   // 2 dbufs x (A0|A1|B0|B1) x 16 KB
  const int tid  = threadIdx.x;
  const int wave = tid >> 6;
  const int lane = tid & 63;
  const int lr = lane & 15;
  const int lg = (lane >> 4) & 3;
  const int wr = wave >> 2;          // 0..1  (M half)
  const int wc = wave & 3;           // 0..3  (N quarter)
  const int m0 = blockIdx.y * 256;
  const int n0 = blockIdx.x * 256;

  // staging addressing: idx = j*512+tid -> row idx>>3, chunk (idx&7)^(row&7)
  const int srow = tid >> 3;                       // 0..63  (+j*64)
  f4v acc[8][4];
#pragma unroll
  for (int m = 0; m < 8; ++m)
#pragma unroll
    for (int n = 0; n < 4; ++n) acc[m][n] = (f4v)0.0f;

  auto STAGE_HT = [&](int k, int p) {   // panel p of K-tile k -> dbuf k&1
    short* base = &LDS[(k & 1)*32768 + p*8192];
#pragma unroll
    for (int j = 0; j < 2; ++j) {
      const int idx = j*512 + tid;
      const int rr = idx >> 3;
      const int sc = (idx & 7) ^ (rr & 7);
      const short* g;
      if (p < 2) g = A  + (size_t)(m0 + p*128 + rr) * K + k*64 + sc*8;
      else       g = BT + (size_t)(n0 + (p - 2)*128 + rr) * K + k*64 + sc*8;
      short* l = base + (j*512 + wave*64) * 8;     // wave-uniform; HW adds lane*16B
      __builtin_amdgcn_global_load_lds((const __attribute__((address_space(1))) void*)g,
                                       (__attribute__((address_space(3))) void*)l, 16, 0, 0);
    }
  };

  const int NT = K >> 6;               // 32
  // prologue: all 4 panels of K-tile 0
#pragma unroll
  for (int p = 0; p < 4; ++p) STAGE_HT(0, p);
  asm volatile("s_waitcnt vmcnt(0)" ::: "memory");
  __builtin_amdgcn_s_barrier();
  __builtin_amdgcn_sched_barrier(0);

  for (int t = 0; t < NT; ++t) {
    const short* db = &LDS[(t & 1)*32768];
    const short* Ap = db + wr*8192;                 // this wave's A panel
    const short* Bp = db + 16384 + (wc >> 1)*8192;  // this wave's B panel
    const int brow0 = (wc & 1)*64;

    s8v a[4][2], b[4][2];
    // ---- phase 0: stage A panels of t+1; read A[0..3], B[0..1]; MFMA (0,0..1)
    if (t + 1 < NT) { STAGE_HT(t+1, 0); STAGE_HT(t+1, 1); }
#pragma unroll
    for (int m = 0; m < 4; ++m) {
      const int rl = m*16 + lr;
#pragma unroll
      for (int ks = 0; ks < 2; ++ks)
        a[m][ks] = *reinterpret_cast<const s8v*>(Ap + rl*64 + (((ks*4 + lg) ^ (rl & 7)) * 8));
    }
#pragma unroll
    for (int n = 0; n < 2; ++n) {
      const int rb = brow0 + n*16 + lr;
#pragma unroll
      for (int ks = 0; ks < 2; ++ks)
        b[n][ks] = *reinterpret_cast<const s8v*>(Bp + rb*64 + (((ks*4 + lg) ^ (rb & 7)) * 8));
    }
    __builtin_amdgcn_s_setprio(1);
#pragma unroll
    for (int m = 0; m < 4; ++m)
#pragma unroll
      for (int n = 0; n < 2; ++n)
#pragma unroll
        for (int ks = 0; ks < 2; ++ks)
          acc[m][n] = __builtin_amdgcn_mfma_f32_16x16x32_bf16(
              __builtin_bit_cast(b8v, a[m][ks]), __builtin_bit_cast(b8v, b[n][ks]),
              acc[m][n], 0, 0, 0);
    __builtin_amdgcn_s_setprio(0);

    // ---- phase 1: stage B panels of t+1; read B[2..3]; MFMA (0, 2..3)
    if (t + 1 < NT) { STAGE_HT(t+1, 2); STAGE_HT(t+1, 3); }
#pragma unroll
    for (int n = 2; n < 4; ++n) {
      const int rb = brow0 + n*16 + lr;
#pragma unroll
      for (int ks = 0; ks < 2; ++ks)
        b[n][ks] = *reinterpret_cast<const s8v*>(Bp + rb*64 + (((ks*4 + lg) ^ (rb & 7)) * 8));
    }
    __builtin_amdgcn_s_setprio(1);
#pragma unroll
    for (int m = 0; m < 4; ++m)
#pragma unroll
      for (int n = 2; n < 4; ++n)
#pragma unroll
        for (int ks = 0; ks < 2; ++ks)
          acc[m][n] = __builtin_amdgcn_mfma_f32_16x16x32_bf16(
              __builtin_bit_cast(b8v, a[m][ks]), __builtin_bit_cast(b8v, b[n][ks]),
              acc[m][n], 0, 0, 0);
    __builtin_amdgcn_s_setprio(0);

    // ---- phase 2: read A[4..7]; MFMA (1, 0..1)
#pragma unroll
    for (int m = 0; m < 4; ++m) {
      const int rl = (m + 4)*16 + lr;
#pragma unroll
      for (int ks = 0; ks < 2; ++ks)
        a[m][ks] = *reinterpret_cast<const s8v*>(Ap + rl*64 + (((ks*4 + lg) ^ (rl & 7)) * 8));
    }
    __builtin_amdgcn_s_setprio(1);
#pragma unroll
    for (int m = 0; m < 4; ++m)
#pragma unroll
      for (int n = 0; n < 2; ++n)
#pragma unroll
        for (int ks = 0; ks < 2; ++ks)
          acc[m + 4][n] = __builtin_amdgcn_mfma_f32_16x16x32_bf16(
              __builtin_bit_cast(b8v, a[m][ks]), __builtin_bit_cast(b8v, b[n][ks]),
              acc[m + 4][n], 0, 0, 0);
    __builtin_amdgcn_s_setprio(0);

    // ---- phase 3: MFMA (1, 2..3)
    __builtin_amdgcn_s_setprio(1);
#pragma unroll
    for (int m = 0; m < 4; ++m)
#pragma unroll
      for (int n = 2; n < 4; ++n)
#pragma unroll
        for (int ks = 0; ks < 2; ++ks)
          acc[m + 4][n] = __builtin_amdgcn_mfma_f32_16x16x32_bf16(
              __builtin_bit_cast(b8v, a[m][ks]), __builtin_bit_cast(b8v, b[n][ks]),
              acc[m + 4][n], 0, 0, 0);
    __builtin_amdgcn_s_setprio(0);

    // ---- iteration boundary: drain (loads 2-3 phases old) + sync
    if (t + 1 < NT) {
      asm volatile("s_waitcnt vmcnt(0)" ::: "memory");
      __builtin_amdgcn_s_barrier();
      __builtin_amdgcn_sched_barrier(0);
    }
  }

  // ---------------- epilogue ----------------
  const int colbase = n0 + wc*64;
  const int rowbase = m0 + wr*128;
  if (MODE == 3 && colbase >= 2560) {
    // V^T: Vt[(col-2560)][row..row+3] short4-packed
#pragma unroll
    for (int m = 0; m < 8; ++m) {
#pragma unroll
      for (int n = 0; n < 4; ++n) {
        const int col = colbase + n*16 + lr - 2560;
        const int row = rowbase + m*16 + lg*4;
        short4 o;
        o.x = f2bs(acc[m][n][0]); o.y = f2bs(acc[m][n][1]);
        o.z = f2bs(acc[m][n][2]); o.w = f2bs(acc[m][n][3]);
        *reinterpret_cast<short4*>(Vt + (size_t)col * M + row) = o;
      }
    }
  } else {
#pragma unroll
    for (int m = 0; m < 8; ++m) {
#pragma unroll
      for (int n = 0; n < 4; ++n) {
        const int col = colbase + n*16 + lr;
#pragma unroll
        for (int i = 0; i < 4; ++i) {
          const int row = rowbase + m*16 + lg*4 + i;
          if (MODE == 1)
            reinterpret_cast<float*>(Cv)[(size_t)row * N + col] = acc[m][n][i];
          else if (col < 2048)
            reinterpret_cast<short*>(Cv)[(size_t)row * 2048 + col] = f2bs(acc[m][n][i]);
          else
            Kv[(size_t)row * 512 + (col - 2048)] = f2bs(acc[m][n][i]);
        }
      }
    }
  }
}

// ---------------- flash attention (R14, frozen) ----------------
__device__ __forceinline__ void stage_tile(short* KsBuf, short* VtBuf,
                                           const short* __restrict__ Kb,
                                           const short* __restrict__ Vtg,
                                           int bT, int kv0, int kvh,
                                           int tid, int wave) {
#pragma unroll
  for (int j = 0; j < 4; ++j) {
    const int f = j*256 + tid;
    const int row = f >> 4, cd = f & 15, cs = cd ^ (row & 7);
    const short* g = Kb + (size_t)(bT + kv0 + row)*512 + kvh*HD_ + cs*8;
    short* l = KsBuf + (j*256 + wave*64) * 8;
    __builtin_amdgcn_global_load_lds((const __attribute__((address_space(1))) void*)g,
                                     (__attribute__((address_space(3))) void*)l, 16, 0, 0);
  }
#pragma unroll
  for (int j = 0; j < 4; ++j) {
    const int f = j*256 + tid;
    const int d = f >> 3, cd = f & 7, cs = cd ^ (d & 7);
    const short* g = Vtg + (size_t)(kvh*HD_ + d)*M_ + bT + kv0 + cs*8;
    short* l = VtBuf + (j*256 + wave*64) * 8;
    __builtin_amdgcn_global_load_lds((const __attribute__((address_space(1))) void*)g,
                                     (__attribute__((address_space(3))) void*)l, 16, 0, 0);
  }
}

#define PHALF 33792   // 32768 O + 512 m + 512 l
#define PGI   67584   // 2 halves

__global__ __launch_bounds__(256, 2) void attn_kernel(const short* __restrict__ Q,
                                                      const short* __restrict__ Kb,
                                                      const short* __restrict__ Vtg,
                                                      const unsigned long long* __restrict__ pmA,
                                                      short* __restrict__ AO,
                                                      char* __restrict__ pbuf) {
  __shared__ alignas(16) short Ks[2][64*128];
  __shared__ alignas(16) short Vt[2][128*64];

  const int bid = blockIdx.x;
  int p, bh, split = 0, half = 0, r;
  if      (bid <  32) { p = 10; bh = bid;       }
  else if (bid <  64) { p = 9;  bh = bid - 32;  }
  else if (bid <  96) { p = 8;  bh = bid - 64;  }
  else if (bid < 160) { p = 15; r = bid - 96;  bh = r >> 1; half = r & 1; split = 1; }
  else if (bid < 192) { p = 7;  bh = bid - 160; }
  else if (bid < 256) { p = 14; r = bid - 192; bh = r >> 1; half = r & 1; split = 1; }
  else if (bid < 320) { p = 13; r = bid - 256; bh = r >> 1; half = r & 1; split = 1; }
  else if (bid < 352) { p = 6;  bh = bid - 320; }
  else if (bid < 416) { p = 12; r = bid - 352; bh = r >> 1; half = r & 1; split = 1; }
  else if (bid < 448) { p = 5;  bh = bid - 416; }
  else if (bid < 512) { p = 11; r = bid - 448; bh = r >> 1; half = r & 1; split = 1; }
  else if (bid < 544) { p = 4;  bh = bid - 512; }
  else if (bid < 576) { p = 3;  bh = bid - 544; }
  else if (bid < 608) { p = 2;  bh = bid - 576; }
  else if (bid < 640) { p = 1;  bh = bid - 608; }
  else                { p = 0;  bh = bid - 640; }

  const int h   = bh & (H_-1);
  const int b   = bh >> 4;
  const int kvh = h & (KV_-1);
  const int nt  = 2*(p+1);
  const int ht  = p + 1;
  const int t0  = (split && half) ? ht : 0;
  const int t1  = split ? (half ? nt : ht) : nt;

  const int tid = threadIdx.x;
  const int wq  = tid >> 6;
  const int lane = tid & 63;
  const int ql  = lane & 31;
  const int hi  = lane >> 5;
  const int bT  = b * T_;
  const int q0  = p * 128;
  const int qrow = q0 + wq*32 + ql;
  const int pmBase = b * 32;
  const float SC = 0.08838834764831845f * 1.4426950408889634f;

  s8v qf[8];
  const size_t qgbase = (size_t)(bT + qrow) * (H_*HD_) + h*HD_;
#pragma unroll
  for (int mm = 0; mm < 8; ++mm)
    qf[mm] = *reinterpret_cast<const s8v*>(Q + qgbase + mm*16 + hi*8);

  f16v oacc[4];
#pragma unroll
  for (int n = 0; n < 4; ++n) oacc[n] = (f16v)0.0f;
  float m_run = -1.0e30f, lsum = 0.0f;

  stage_tile(Ks[0], Vt[0], Kb, Vtg, bT, t0*64, kvh, tid, wq);
  unsigned long long pm_cur = pmA[pmBase + t0];
  int cur = 0;
  for (int t = t0; t < t1; ++t) {
    __syncthreads();
    if (t + 1 < t1)
      stage_tile(Ks[cur^1], Vt[cur^1], Kb, Vtg, bT, (t+1)*64, kvh, tid, wq);
    const unsigned long long pm_next = (t + 1 < t1) ? pmA[pmBase + t + 1] : 0ull;
    const int kv0 = t * 64;
    const char* KsC = reinterpret_cast<const char*>(Ks[cur]);
    const char* VtC = reinterpret_cast<const char*>(Vt[cur]);

    f16v s0a = (f16v)0.0f, s0b = (f16v)0.0f, s1a = (f16v)0.0f, s1b = (f16v)0.0f;
#pragma unroll
    for (int mm = 0; mm < 4; ++mm) {
      const int row0 = ql, row1 = 32 + ql;
      s8v kf0 = *reinterpret_cast<const s8v*>(KsC +
          ((row0*256 + mm*32 + hi*16) ^ ((row0 & 7) << 4)));
      s8v kf1 = *reinterpret_cast<const s8v*>(KsC +
          ((row1*256 + mm*32 + hi*16) ^ ((row1 & 7) << 4)));
      s0a = __builtin_amdgcn_mfma_f32_32x32x16_bf16(
          __builtin_bit_cast(b8v, kf0), __builtin_bit_cast(b8v, qf[mm]), s0a, 0, 0, 0);
      s1a = __builtin_amdgcn_mfma_f32_32x32x16_bf16(
          __builtin_bit_cast(b8v, kf1), __builtin_bit_cast(b8v, qf[mm]), s1a, 0, 0, 0);
    }
#pragma unroll
    for (int mm = 4; mm < 8; ++mm) {
      const int row0 = ql, row1 = 32 + ql;
      s8v kf0 = *reinterpret_cast<const s8v*>(KsC +
          ((row0*256 + mm*32 + hi*16) ^ ((row0 & 7) << 4)));
      s8v kf1 = *reinterpret_cast<const s8v*>(KsC +
          ((row1*256 + mm*32 + hi*16) ^ ((row1 & 7) << 4)));
      s0b = __builtin_amdgcn_mfma_f32_32x32x16_bf16(
          __builtin_bit_cast(b8v, kf0), __builtin_bit_cast(b8v, qf[mm]), s0b, 0, 0, 0);
      s1b = __builtin_amdgcn_mfma_f32_32x32x16_bf16(
          __builtin_bit_cast(b8v, kf1), __builtin_bit_cast(b8v, qf[mm]), s1b, 0, 0, 0);
    }
    f16v sacc[2];
    sacc[0] = s0a + s0b;
    sacc[1] = s1a + s1b;

    float tm[16];
#pragma unroll
    for (int rr = 0; rr < 16; ++rr) tm[rr] = fmaxf(sacc[0][rr], sacc[1][rr]);
#pragma unroll
    for (int rr = 0; rr < 8; ++rr) tm[rr] = fmaxf(tm[rr], tm[rr+8]);
#pragma unroll
    for (int rr = 0; rr < 4; ++rr) tm[rr] = fmaxf(tm[rr], tm[rr+4]);
    tm[0] = fmaxf(fmaxf(tm[0], tm[1]), fmaxf(tm[2], tm[3]));
    const float mx = fmaxf(tm[0], __shfl_xor(tm[0], 32));

    if (!__all(mx <= m_run + 20.0f)) {
      const float mn = fmaxf(m_run, mx);
      const float corr = exp2f((m_run - mn) * SC);
      lsum *= corr;
#pragma unroll
      for (int n = 0; n < 4; ++n)
#pragma unroll
        for (int rr = 0; rr < 16; ++rr) oacc[n][rr] *= corr;
      m_run = mn;
    }
    const float nm = -m_run * SC;
    const bool fast = (kv0 + 63 <= q0 + wq*32) && (pm_cur == ~0ull);

    float psum = 0.0f;
#pragma unroll
    for (int kb = 0; kb < 2; ++kb) {
      float pv[16];
#pragma unroll
      for (int rr = 0; rr < 16; ++rr)
        pv[rr] = exp2f(fmaf(sacc[kb][rr], SC, nm));
      if (!fast) {
        const int th = qrow - kv0 - kb*32 - 4*hi;
        const unsigned cw = (th >= 28) ? 0xffffffffu
                          : ((th < 0) ? 0u : ((2u << th) - 1u));
        const unsigned vm = cw & (unsigned)(pm_cur >> (kb*32 + 4*hi));
#pragma unroll
        for (int rr = 0; rr < 16; ++rr) {
          const int C = (rr & 3) + 8*(rr >> 2);
          pv[rr] = ((vm >> C) & 1u) ? pv[rr] : 0.0f;
        }
      }
      float ps[8];
#pragma unroll
      for (int rr = 0; rr < 8; ++rr) ps[rr] = pv[rr] + pv[rr+8];
#pragma unroll
      for (int rr = 0; rr < 4; ++rr) ps[rr] += ps[rr+4];
      psum += (ps[0] + ps[1]) + (ps[2] + ps[3]);

      unsigned pa = cvtpk(pv[0],  pv[1]),  pb = cvtpk(pv[2],  pv[3]);
      unsigned pc = cvtpk(pv[4],  pv[5]),  pd = cvtpk(pv[6],  pv[7]);
      unsigned pe = cvtpk(pv[8],  pv[9]),  pf_ = cvtpk(pv[10], pv[11]);
      unsigned pg = cvtpk(pv[12], pv[13]), ph = cvtpk(pv[14], pv[15]);
      plswap2(pa, pc);  plswap2(pb, pd);
      plswap2(pe, pg);  plswap2(pf_, ph);
      u4v pw0 = {pa, pb, pc, pd};
      u4v pw1 = {pe, pf_, pg, ph};

#pragma unroll
      for (int s = 0; s < 2; ++s) {
        const b8v pf = __builtin_bit_cast(b8v, s ? pw1 : pw0);
        const int ks = 2*kb + s;
#pragma unroll
        for (int n = 0; n < 4; ++n) {
          const int d = n*32 + ql;
          s8v vf = *reinterpret_cast<const s8v*>(VtC +
              ((d*128 + ks*32 + hi*16) ^ ((d & 7) << 4)));
          oacc[n] = __builtin_amdgcn_mfma_f32_32x32x16_bf16(
              __builtin_bit_cast(b8v, vf), pf, oacc[n], 0, 0, 0);
        }
      }
    }
    lsum += psum + __shfl_xor(psum, 32);
    pm_cur = pm_next;
    cur ^= 1;
  }

  if (!split) {
    const float inv = 1.0f / fmaxf(lsum, 1.0e-37f);
    const size_t obase = (size_t)(bT + qrow) * (H_*HD_) + h*HD_;
#pragma unroll
    for (int n = 0; n < 4; ++n) {
#pragma unroll
      for (int j = 0; j < 4; ++j) {
        short4 o;
        o.x = f2bs(oacc[n][4*j+0] * inv);
        o.y = f2bs(oacc[n][4*j+1] * inv);
        o.z = f2bs(oacc[n][4*j+2] * inv);
        o.w = f2bs(oacc[n][4*j+3] * inv);
        *reinterpret_cast<short4*>(AO + obase + n*32 + 8*j + 4*hi) = o;
      }
    }
  } else {
    char* pg = pbuf + (size_t)(bh*5 + (p - 11)) * PGI + half * PHALF;
    short* pO = (short*)pg;
    float* pM = (float*)(pg + 32768);
    float* pL = (float*)(pg + 33280);
    const int row = wq*32 + ql;
#pragma unroll
    for (int n = 0; n < 4; ++n) {
#pragma unroll
      for (int j = 0; j < 4; ++j) {
        short4 o;
        o.x = f2bs(oacc[n][4*j+0]);
        o.y = f2bs(oacc[n][4*j+1]);
        o.z = f2bs(oacc[n][4*j+2]);
        o.w = f2bs(oacc[n][4*j+3]);
        *reinterpret_cast<short4*>(pO + row*128 + n*32 + 8*j + 4*hi) = o;
      }
    }
    if (hi == 0) { pM[row] = m_run; pL[row] = lsum; }
  }
}

// ---------------- combine (R14, frozen) ----------------
__global__ __launch_bounds__(256) void combine_kernel(const char* __restrict__ pbuf,
                                                      short* __restrict__ AO) {
  const int gi = blockIdx.x;
  const int bh = gi / 5, pp = gi % 5, p = 11 + pp;
  const int h = bh & (H_-1), b = bh >> 4;
  const char* g0 = pbuf + (size_t)gi * PGI;
  const char* g1 = g0 + PHALF;
  const int t = threadIdx.x;
  const int row = t >> 1, dh = (t & 1) * 64;
  const float SC = 0.08838834764831845f * 1.4426950408889634f;

  const float m1 = ((const float*)(g0 + 32768))[row];
  const float l1 = ((const float*)(g0 + 33280))[row];
  const float m2 = ((const float*)(g1 + 32768))[row];
  const float l2 = ((const float*)(g1 + 33280))[row];
  const float m  = fmaxf(m1, m2);
  const float w1 = exp2f((m1 - m) * SC);
  const float w2 = exp2f((m2 - m) * SC);
  const float inv = 1.0f / fmaxf(w1*l1 + w2*l2, 1.0e-37f);

  const short* O1 = (const short*)g0 + row*128 + dh;
  const short* O2 = (const short*)g1 + row*128 + dh;
  short* dst = AO + (size_t)(b*T_ + p*128 + row) * (H_*HD_) + h*HD_ + dh;
#pragma unroll
  for (int c = 0; c < 8; ++c) {
    s8v a = *reinterpret_cast<const s8v*>(O1 + c*8);
    s8v v = *reinterpret_cast<const s8v*>(O2 + c*8);
    s8v o;
#pragma unroll
    for (int e = 0; e < 8; ++e)
      o[e] = f2bs((w1 * bs2f(a[e]) + w2 * bs2f(v[e])) * inv);
    *reinterpret_cast<s8v*>(dst + c*8) = o;
  }
}

// ---------------- launcher ----------------
extern "C" void kernel_launch(void* const* d_in, const int* in_sizes, int n_in,
                              void* d_out, int out_size, void* d_ws, size_t ws_size,
                              hipStream_t stream) {
  const float* hs = (const float*)d_in[0];
  const int*  ids = (const int*)d_in[1];
  const float* Wq = (const float*)d_in[2];
  const float* Wk = (const float*)d_in[3];
  const float* Wv = (const float*)d_in[4];
  const float* Wo = (const float*)d_in[5];
  char* ws = (char*)d_ws;

  short* hsb = (short*)(ws);                          // 16 MiB, reused as AO
  short* WT  = (short*)(ws + (16u << 20));            // 12 MiB, reused as pbuf after QKV
  short* WoT = (short*)(ws + (28u << 20));            // 8 MiB
  short* Qb  = (short*)(ws + (36u << 20));            // 16 MiB
  short* Kb  = (short*)(ws + (52u << 20));            // 4 MiB
  short* Vtg = (short*)(ws + (56u << 20));            // 4 MiB
  short* AO  = hsb;
  char*  pbuf = (char*)WT;
  float* out = (float*)d_out;
  unsigned long long* pmA = (unsigned long long*)d_out;

  prep_kernel<<<dim3(18432), dim3(32, 8), 0, stream>>>(hs, Wq, Wk, Wv, Wo, hsb, WT, WoT, ids, pmA);

  gemm_bt_kernel<3><<<dim3(3072/256, 4096/256), dim3(512), 0, stream>>>(
      hsb, WT, Qb, Kb, Vtg, 4096, 3072, 2048);

  attn_kernel<<<dim3(672), dim3(256), 0, stream>>>(Qb, Kb, Vtg, pmA, AO, pbuf);
  combine_kernel<<<dim3(160), dim3(256), 0, stream>>>(pbuf, AO);

  gemm_bt_kernel<1><<<dim3(2048/256, 4096/256), dim3(512), 0, stream>>>(
      AO, WoT, out, nullptr, nullptr, 4096, 2048, 2048);
}